// Round 7
// baseline (272.912 us; speedup 1.0000x reference)
//
#include <hip/hip_runtime.h>
#include <math.h>

#define N_NODES 50000
#define E_EDGES 1600000
#define IN_CH   34
#define NEG     0.2f
#define NB      196          // coarse buckets: dst>>8
#define CAP     10000        // bucket capacity (E[8163], sigma~90 -> 20 sigma)

typedef __attribute__((ext_vector_type(2))) float fv2;

static __device__ __forceinline__ unsigned short f2bf(float f) {
    unsigned int u = __float_as_uint(f);
    u += 0x7fffu + ((u >> 16) & 1u);
    return (unsigned short)(u >> 16);
}
static __device__ __forceinline__ float bflo(unsigned int u) {
    return __uint_as_float(u << 16);
}
static __device__ __forceinline__ float bfhi(unsigned int u) {
    return __uint_as_float(u & 0xffff0000u);
}
static __device__ __forceinline__ float lrelu_exp(float e) {
    return expf(e > 0.f ? e : NEG * e);
}

// 256-thread block exclusive scan. wsum = int[4] LDS scratch.
static __device__ __forceinline__ int scan256_excl(int v, int* wsum) {
    const int lane = threadIdx.x & 63, wv = threadIdx.x >> 6;
    int x = v;
    #pragma unroll
    for (int off = 1; off < 64; off <<= 1) {
        int y = __shfl_up(x, off);
        if (lane >= off) x += y;
    }
    if (lane == 63) wsum[wv] = x;
    __syncthreads();
    if (threadIdx.x < 4) {
        int s = wsum[threadIdx.x];
        #pragma unroll
        for (int off = 1; off < 4; off <<= 1) {
            int y = __shfl_up(s, off);
            if ((int)threadIdx.x >= off) s += y;
        }
        wsum[threadIdx.x] = s;
    }
    __syncthreads();
    const int woff = wv ? wsum[wv - 1] : 0;
    return woff + x - v;
}

// ---------------------------------------------------------------------------
// Bin edges into bucket-strided `binned` ((dst<<16)|src). The count atomic's
// return value IS the edge's local rank -> direct placement, no reorder pass.
// 4096 edges/block, 26 KB LDS.
// ---------------------------------------------------------------------------
__global__ __launch_bounds__(256) void k_bin(
    const int* __restrict__ srcA, const int* __restrict__ dstA,
    int* __restrict__ gcur, unsigned int* __restrict__ binned)
{
    __shared__ unsigned int raw[4096];      // 16 KB
    __shared__ unsigned short rnk[4096];    // 8 KB
    __shared__ int cnt[256], cur[256];
    const int tid = threadIdx.x;
    cnt[tid] = 0;
    __syncthreads();
    const int base = blockIdx.x * 4096;
    #pragma unroll
    for (int i = 0; i < 16; ++i) {
        const int e = base + i * 256 + tid;
        if (e < E_EDGES) {
            const int d = dstA[e], s = srcA[e];
            raw[i * 256 + tid] = ((unsigned int)d << 16) | (unsigned int)s;
            rnk[i * 256 + tid] = (unsigned short)atomicAdd(&cnt[d >> 8], 1);
        }
    }
    __syncthreads();
    const int v = cnt[tid];
    cur[tid] = (tid < NB && v > 0) ? (tid * CAP + atomicAdd(&gcur[tid], v)) : 0;
    __syncthreads();
    const int mE = min(4096, E_EDGES - base);
    for (int p = tid; p < mE; p += 256) {
        const unsigned int u = raw[p];
        binned[cur[u >> 24] + rnk[p]] = u;
    }
}

// Per-bucket fine sort (rank-from-atomic) -> sorted_src (ushort) + rowspan.
__global__ __launch_bounds__(256) void k_fine(
    const int* __restrict__ gcur, const unsigned int* __restrict__ binned,
    int2* __restrict__ rowspan, unsigned short* __restrict__ sorted_src)
{
    __shared__ unsigned int sbin[CAP];      // 40 KB
    __shared__ unsigned short rnk[CAP];     // 20 KB
    __shared__ int cnt[256], sbase[256];
    __shared__ int wsum[4];
    const int tid = threadIdx.x;
    const int b = blockIdx.x;
    const int bbase = b * CAP;
    const int cntb = gcur[b];
    cnt[tid] = 0;
    __syncthreads();
    for (int p = tid; p < cntb; p += 256) {
        const unsigned int u = binned[bbase + p];
        sbin[p] = u;
        rnk[p] = (unsigned short)atomicAdd(&cnt[(u >> 16) & 255], 1);
    }
    __syncthreads();
    const int v = cnt[tid];
    const int excl = scan256_excl(v, wsum);
    const int node = b * 256 + tid;
    if (node < N_NODES) rowspan[node] = make_int2(bbase + excl, bbase + excl + v);
    sbase[tid] = excl;
    __syncthreads();
    for (int p = tid; p < cntb; p += 256) {
        const unsigned int u = sbin[p];
        sorted_src[bbase + sbase[(u >> 16) & 255] + rnk[p]] =
            (unsigned short)(u & 0xffffu);
    }
}

// ---------------------------------------------------------------------------
// Layer 1 node pre-pass (register-tiled): xw1b = bf16(x @ W1) [N,128];
// logit halves al_s/al_d [N,2]. Block 0 also packs W2 -> bf16 pairs w2p.
// ---------------------------------------------------------------------------
__global__ __launch_bounds__(256) void k_node1(
    const float* __restrict__ x, const float* __restrict__ W1,
    const float* __restrict__ a_src, const float* __restrict__ a_dst,
    unsigned short* __restrict__ xw1b,
    float* __restrict__ al_s, float* __restrict__ al_d,
    const float* __restrict__ W2, unsigned int* __restrict__ w2p)
{
    __shared__ float sW[IN_CH * 132];
    __shared__ float sx[32 * 35];
    __shared__ float sas[128], sad[128];
    const int tid = threadIdx.x;
    if (blockIdx.x == 0) {
        // pack W2[128][64] -> w2p[k2*64+c] = (bf16(W2[2k2][c]), bf16(W2[2k2+1][c]))
        for (int i = tid; i < 4096; i += 256) {
            const int k2 = i >> 6, c = i & 63;
            const unsigned int lo = f2bf(W2[(2 * k2) * 64 + c]);
            const unsigned int hi = f2bf(W2[(2 * k2 + 1) * 64 + c]);
            w2p[i] = lo | (hi << 16);
        }
    }
    for (int i = tid; i < IN_CH * 128; i += 256) {
        int k = i >> 7, c = i & 127;
        sW[k * 132 + c] = W1[i];
    }
    if (tid < 128) { sas[tid] = a_src[tid]; sad[tid] = a_dst[tid]; }
    const int n0 = blockIdx.x * 32;
    for (int i = tid; i < 32 * IN_CH; i += 256) {
        int n = i / IN_CH;
        sx[n * 35 + (i - n * IN_CH)] = (n0 + n < N_NODES) ? x[n0 * IN_CH + i] : 0.f;
    }
    __syncthreads();

    const int tc = tid & 31, tn = tid >> 5;
    float acc[4][4] = {{0.f}};
    for (int k = 0; k < IN_CH; ++k) {
        const float4 wv = *reinterpret_cast<const float4*>(&sW[k * 132 + 4 * tc]);
        #pragma unroll
        for (int j = 0; j < 4; ++j) {
            const float hj = sx[(4 * tn + j) * 35 + k];
            acc[j][0] += hj * wv.x; acc[j][1] += hj * wv.y;
            acc[j][2] += hj * wv.z; acc[j][3] += hj * wv.w;
        }
    }
    #pragma unroll
    for (int j = 0; j < 4; ++j) {
        const int node = n0 + 4 * tn + j;
        float ps = 0.f, pd = 0.f;
        #pragma unroll
        for (int c = 0; c < 4; ++c) {
            ps += acc[j][c] * sas[4 * tc + c];
            pd += acc[j][c] * sad[4 * tc + c];
        }
        #pragma unroll
        for (int off = 1; off < 16; off <<= 1) {
            ps += __shfl_xor(ps, off);
            pd += __shfl_xor(pd, off);
        }
        if (node < N_NODES) {
            if ((tc & 15) == 0) {
                int h = tc >> 4;
                al_s[node * 2 + h] = ps;
                al_d[node * 2 + h] = pd;
            }
            ushort4 u;
            u.x = f2bf(acc[j][0]); u.y = f2bf(acc[j][1]);
            u.z = f2bf(acc[j][2]); u.w = f2bf(acc[j][3]);
            *reinterpret_cast<ushort4*>(&xw1b[node * 128 + 4 * tc]) = u;
        }
    }
}

// ---------------------------------------------------------------------------
// Layer 1 gather + fused layer-2 node pre-pass. One wave per node (grid is
// exact: 12500 blocks x 4 waves = 50000). Main loop = R6 structure (pair-
// packed per-head (offset,weight) LDS, fv2 accumulators). Epilogue computes
// h row in LDS, then xw2 = bf16(h @ W2) per lane + layer-2 logits.
// hbuf never touches global memory.
// ---------------------------------------------------------------------------
__global__ __launch_bounds__(256) void k_gather1(
    const int2* __restrict__ rowspan, const unsigned short* __restrict__ sorted_src,
    const unsigned int* __restrict__ xw1u,    // 64 uints per row
    const float* __restrict__ al_s, const float* __restrict__ al_d,
    const float* __restrict__ b1, const unsigned int* __restrict__ w2p,
    const float* __restrict__ as2, const float* __restrict__ ad2,
    unsigned short* __restrict__ xw2b,
    float* __restrict__ al_s2, float* __restrict__ al_d2)
{
    __shared__ unsigned int sW2[4096];        // 16 KB: bf16-pair W2
    __shared__ float4 AB[2][4][32];           // 4 KB
    __shared__ float2 sh2[4][64];             // 2 KB: h row per wave
    const int tid = threadIdx.x;
    for (int i = tid; i < 4096; i += 256) sW2[i] = w2p[i];
    __syncthreads();

    const int wave = tid >> 6;
    const int lane = tid & 63;
    const int node = blockIdx.x * 4 + wave;
    const int2 span = rowspan[node];
    const int head = lane >> 5;

    const float2 ald  = *reinterpret_cast<const float2*>(&al_d[node * 2]);
    const float2 als0 = *reinterpret_cast<const float2*>(&al_s[node * 2]);
    const float w0h0 = lrelu_exp(als0.x + ald.x);
    const float w0h1 = lrelu_exp(als0.y + ald.y);
    const float wself = head ? w0h1 : w0h0;

    const unsigned int su = xw1u[node * 64 + lane];
    fv2 accX = { wself * bflo(su), wself * bfhi(su) };
    fv2 accY = { 0.f, 0.f };
    float dv0 = 0.f, dv1 = 0.f;
    const float4* ABh = AB[head][wave];

    for (int base = span.x; base < span.y; base += 64) {
        const int rem = span.y - base;
        const int m = rem < 64 ? rem : 64;
        const int mp = (m + 1) & ~1;
        if (lane < m) {
            const int s = sorted_src[base + lane];
            const float2 als = *reinterpret_cast<const float2*>(&al_s[s * 2]);
            const float w0 = lrelu_exp(als.x + ald.x);
            const float w1 = lrelu_exp(als.y + ald.y);
            dv0 += w0; dv1 += w1;
            const float offf = __int_as_float(s << 6);
            ((float2*)&AB[0][wave][lane >> 1])[lane & 1] = make_float2(offf, w0);
            ((float2*)&AB[1][wave][lane >> 1])[lane & 1] = make_float2(offf, w1);
        } else if (lane < mp) {
            const float offf = __int_as_float(node << 6);
            ((float2*)&AB[0][wave][lane >> 1])[lane & 1] = make_float2(offf, 0.f);
            ((float2*)&AB[1][wave][lane >> 1])[lane & 1] = make_float2(offf, 0.f);
        }
        const int P = mp >> 1;
        int p = 0;
        for (; p + 4 <= P; p += 4) {
            const float4 q0 = ABh[p + 0];
            const float4 q1 = ABh[p + 1];
            const float4 q2 = ABh[p + 2];
            const float4 q3 = ABh[p + 3];
            const unsigned int a0 = xw1u[__float_as_int(q0.x) + lane];
            const unsigned int b0 = xw1u[__float_as_int(q0.z) + lane];
            const unsigned int a1 = xw1u[__float_as_int(q1.x) + lane];
            const unsigned int b1v = xw1u[__float_as_int(q1.z) + lane];
            const unsigned int a2 = xw1u[__float_as_int(q2.x) + lane];
            const unsigned int b2 = xw1u[__float_as_int(q2.z) + lane];
            const unsigned int a3 = xw1u[__float_as_int(q3.x) + lane];
            const unsigned int b3 = xw1u[__float_as_int(q3.z) + lane];
            fv2 f;
            f.x = bflo(a0); f.y = bfhi(a0); accX += f * q0.y;
            f.x = bflo(b0); f.y = bfhi(b0); accY += f * q0.w;
            f.x = bflo(a1); f.y = bfhi(a1); accX += f * q1.y;
            f.x = bflo(b1v); f.y = bfhi(b1v); accY += f * q1.w;
            f.x = bflo(a2); f.y = bfhi(a2); accX += f * q2.y;
            f.x = bflo(b2); f.y = bfhi(b2); accY += f * q2.w;
            f.x = bflo(a3); f.y = bfhi(a3); accX += f * q3.y;
            f.x = bflo(b3); f.y = bfhi(b3); accY += f * q3.w;
        }
        for (; p < P; ++p) {
            const float4 q = ABh[p];
            const unsigned int a = xw1u[__float_as_int(q.x) + lane];
            const unsigned int b = xw1u[__float_as_int(q.z) + lane];
            fv2 f;
            f.x = bflo(a); f.y = bfhi(a); accX += f * q.y;
            f.x = bflo(b); f.y = bfhi(b); accY += f * q.w;
        }
    }
    accX += accY;
    #pragma unroll
    for (int off = 32; off; off >>= 1) {
        dv0 += __shfl_xor(dv0, off);
        dv1 += __shfl_xor(dv1, off);
    }
    const float den = head ? (dv1 + w0h1) : (dv0 + w0h0);
    const float2 bv = *reinterpret_cast<const float2*>(&b1[2 * lane]);
    float o0 = accX.x / den + bv.x;
    float o1 = accX.y / den + bv.y;
    o0 = o0 > 0.f ? o0 : 0.f;
    o1 = o1 > 0.f ? o1 : 0.f;

    // ---- fused layer-2 node pre-pass: xw2[c] = h . W2[:,c], c = lane ----
    sh2[wave][lane] = make_float2(o0, o1);    // wave-local, no barrier needed
    float a2acc = 0.f;
    #pragma unroll 4
    for (int k2 = 0; k2 < 64; ++k2) {
        const float2 hp = sh2[wave][k2];      // broadcast read
        const unsigned int wv2 = sW2[k2 * 64 + lane];
        a2acc += hp.x * bflo(wv2) + hp.y * bfhi(wv2);
    }
    float ps2 = a2acc * as2[lane];
    float pd2 = a2acc * ad2[lane];
    #pragma unroll
    for (int off = 32; off; off >>= 1) {
        ps2 += __shfl_xor(ps2, off);
        pd2 += __shfl_xor(pd2, off);
    }
    xw2b[node * 64 + lane] = f2bf(a2acc);
    if (lane == 0) { al_s2[node] = ps2; al_d2[node] = pd2; }
}

// ---------------------------------------------------------------------------
// Layer 2 gather: half-wave per edge pair, pair-packed (offset,weight) LDS,
// fv2 accumulators. out = acc/den + b2.
// ---------------------------------------------------------------------------
__global__ __launch_bounds__(256) void k_gather2(
    const int2* __restrict__ rowspan, const unsigned short* __restrict__ sorted_src,
    const unsigned int* __restrict__ xw2u,    // 32 uints per row
    const float* __restrict__ al_s, const float* __restrict__ al_d,
    const float* __restrict__ b2, float* __restrict__ out)
{
    __shared__ float4 AB[4][32];
    const int wave = threadIdx.x >> 6;
    const int lane = threadIdx.x & 63;
    const int node = blockIdx.x * 4 + wave;
    const int2 span = rowspan[node];
    const int li = lane & 31, hsel = lane >> 5;

    const float ald = al_d[node];
    const float w0s = lrelu_exp(al_s[node] + ald);
    const unsigned int su = xw2u[node * 32 + li];
    const float wself = hsel ? 0.f : w0s;
    fv2 acc = { wself * bflo(su), wself * bfhi(su) };
    float dv = 0.f;
    const float4* ABw = AB[wave];

    for (int base = span.x; base < span.y; base += 64) {
        const int rem = span.y - base;
        const int m = rem < 64 ? rem : 64;
        const int mp = (m + 3) & ~3;
        if (lane < m) {
            const int s = sorted_src[base + lane];
            const float w = lrelu_exp(al_s[s] + ald);
            dv += w;
            ((float2*)&AB[wave][lane >> 1])[lane & 1] =
                make_float2(__int_as_float(s << 5), w);
        } else if (lane < mp) {
            ((float2*)&AB[wave][lane >> 1])[lane & 1] =
                make_float2(__int_as_float(node << 5), 0.f);
        }
        const int P = mp >> 1;                // even
        int p = hsel;
        for (; p + 2 < P; p += 4) {
            const float4 qA = ABw[p];
            const float4 qB = ABw[p + 2];
            const unsigned int aA = xw2u[__float_as_int(qA.x) + li];
            const unsigned int bA = xw2u[__float_as_int(qA.z) + li];
            const unsigned int aB = xw2u[__float_as_int(qB.x) + li];
            const unsigned int bB = xw2u[__float_as_int(qB.z) + li];
            fv2 f;
            f.x = bflo(aA); f.y = bfhi(aA); acc += f * qA.y;
            f.x = bflo(bA); f.y = bfhi(bA); acc += f * qA.w;
            f.x = bflo(aB); f.y = bfhi(aB); acc += f * qB.y;
            f.x = bflo(bB); f.y = bfhi(bB); acc += f * qB.w;
        }
        for (; p < P; p += 2) {
            const float4 q = ABw[p];
            const unsigned int a = xw2u[__float_as_int(q.x) + li];
            const unsigned int b = xw2u[__float_as_int(q.z) + li];
            fv2 f;
            f.x = bflo(a); f.y = bfhi(a); acc += f * q.y;
            f.x = bflo(b); f.y = bfhi(b); acc += f * q.w;
        }
    }
    acc.x += __shfl_xor(acc.x, 32);
    acc.y += __shfl_xor(acc.y, 32);
    #pragma unroll
    for (int off = 32; off; off >>= 1) dv += __shfl_xor(dv, off);
    if (lane < 32) {
        const float den = dv + w0s;
        const float2 bv = *reinterpret_cast<const float2*>(&b2[2 * li]);
        *reinterpret_cast<float2*>(&out[node * 64 + 2 * li]) =
            make_float2(acc.x / den + bv.x, acc.y / den + bv.y);
    }
}

extern "C" void kernel_launch(void* const* d_in, const int* in_sizes, int n_in,
                              void* d_out, int out_size, void* d_ws, size_t ws_size,
                              hipStream_t stream)
{
    const float* x   = (const float*)d_in[0];
    const int*   ei  = (const int*)d_in[1];
    const float* W1  = (const float*)d_in[2];
    const float* as1 = (const float*)d_in[3];
    const float* ad1 = (const float*)d_in[4];
    const float* b1  = (const float*)d_in[5];
    const float* W2  = (const float*)d_in[6];
    const float* as2 = (const float*)d_in[7];
    const float* ad2 = (const float*)d_in[8];
    const float* b2  = (const float*)d_in[9];
    float* out = (float*)d_out;

    const int* srcA = ei;
    const int* dstA = ei + E_EDGES;

    // Workspace layout (bytes). Total ~32.7 MB.
    char* ws = (char*)d_ws;
    int2*           rowspan    = (int2*)(ws);                          // 400,000 (pad 409,600)
    unsigned short* sorted_src = (unsigned short*)(ws + 409600);       // 3.92 MB (pad 3,932,160)
    int*            gcur       = (int*)(ws + 4341760);                 // 784 B (pad 2048)
    float*          al_s1      = (float*)(ws + 4343808);               // 400 KB (pad 409,600)
    float*          al_d1      = (float*)(ws + 4753408);               // 409,600
    float*          al_s2      = (float*)(ws + 5163008);               // 204,800
    float*          al_d2      = (float*)(ws + 5367808);               // 204,800
    unsigned short* xw1b       = (unsigned short*)(ws + 5572608);      // 12.8 MB (pad 12,804,096)
    unsigned int*   binned     = (unsigned int*)(ws + 18376704);       // 7.84 MB (pad 7,843,840)
    unsigned short* xw2b       = (unsigned short*)(ws + 26220544);     // 6.4 MB
    unsigned int*   w2p        = (unsigned int*)(ws + 32620544);       // 16 KB

    hipMemsetAsync(gcur, 0, NB * sizeof(int), stream);
    hipLaunchKernelGGL(k_bin, dim3((E_EDGES + 4095) / 4096), dim3(256), 0, stream,
                       srcA, dstA, gcur, binned);
    hipLaunchKernelGGL(k_node1, dim3((N_NODES + 31) / 32), dim3(256), 0, stream,
                       x, W1, as1, ad1, xw1b, al_s1, al_d1, W2, w2p);
    hipLaunchKernelGGL(k_fine, dim3(NB), dim3(256), 0, stream,
                       gcur, binned, rowspan, sorted_src);
    hipLaunchKernelGGL(k_gather1, dim3(N_NODES / 4), dim3(256), 0, stream,
                       rowspan, sorted_src, (const unsigned int*)xw1b,
                       al_s1, al_d1, b1, w2p, as2, ad2, xw2b, al_s2, al_d2);
    hipLaunchKernelGGL(k_gather2, dim3(N_NODES / 4), dim3(256), 0, stream,
                       rowspan, sorted_src, (const unsigned int*)xw2b,
                       al_s2, al_d2, b2, out);
}